// Round 1
// baseline (138.237 us; speedup 1.0000x reference)
//
#include <hip/hip_runtime.h>
#include <math.h>

#define NN 200000
#define DD 64
#define BB 4096
#define KK 128
#define WW 20
#define HH 128
#define TPB 512
#define RPB 4    // targets per block; 8 waves = 2 waves per target

#define INV2PI 0.15915494309189535f

__device__ __forceinline__ float fast_rcp(float x) { return __builtin_amdgcn_rcpf(x); }
__device__ __forceinline__ float fast_rsq(float x) { return __builtin_amdgcn_rsqf(x); }

// Fully-fused pipeline, occupancy-doubled: 1024 blocks x 512 threads,
// 4 targets/block, TWO waves per target (4 blocks/CU -> 32 waves/CU).
//   pre-A : 1 gather slot/thread into packed dtg{dt,g,wk,-}; hws on waves 4-5;
//           per-wave target encodings on waves 0-3 (straight into tile).
//   phase1: 1 slot/thread, full 64-dim norm+att in-lane (d=0 peeled),
//           wk written into dtg.z (single ds_write_b32).
//   hist  : threads 0-127, float4 loads (4 cols x 20 taps) into tile 0-127.
//   phase3: wave pair (2r,2r+1) owns target r, 64 k's each (lane=dim),
//           1/2pi folded into params -> raw v_cos; combine via p3p + barrier.
//   GEMM  : relu(tile @ W^T), W chunk-staged in LDS (pad-33), 1 row/thread.
// feat4 never touches HBM; single launch.
__global__ __launch_bounds__(512, 8) void fused(
    const float* __restrict__ adj_time, const float* __restrict__ gc,
    const float* __restrict__ cur_time, const float* __restrict__ neigh_mask,
    const float* __restrict__ hist_feat, const float* __restrict__ hist_time,
    const float* __restrict__ t2v_w, const float* __restrict__ t2v_b,
    const float* __restrict__ node_w, const float* __restrict__ node_b,
    const float* __restrict__ att_w, const float* __restrict__ att_b,
    const float* __restrict__ weight,
    const int* __restrict__ targets, const int* __restrict__ neigh_idx,
    float* __restrict__ out)
{
    const int b0   = blockIdx.x * RPB;
    const int tid  = threadIdx.x;
    const int lane = tid & 63;
    const int wv   = tid >> 6;          // wave id 0..7

    __shared__ float4 dtg[RPB * KK];    // {dt, g, wk, unused}              8 KB
    __shared__ float  hws[RPB][WW];     // history decay weights          320 B
    __shared__ float  stL[RPB];         // target att-dot per row
    __shared__ float  p3p[RPB][DD];     // phase-3 odd-wave partials        1 KB
    __shared__ float  tile[RPB * 256];  // feat4 rows                       4 KB
    __shared__ float  wl[128 * 33];     // W chunk [128 h][32 j], pad 33  ~17 KB

    const float t = cur_time[0];

    // ---- pre-A: one gather slot per thread (slot = r*128 + k = tid) ----
    const int   slot = tid;
    const int   idx  = neigh_idx[b0 * KK + slot];
    const float m    = neigh_mask[b0 * KK + slot];
    const float at   = adj_time[idx];
    const float g    = gc[idx];
    const float dt   = fabsf(t - at);
    const float ts   = fast_rcp(2.0f * __logf(2.71828182845904523536f + (t - at)));
    dtg[slot] = make_float4(dt, g, 0.f, 0.f);

    // ---- pre-A: history decay weights (waves 4-5 region) ----
    if (tid >= 256 && tid < 256 + RPB * WW) {
        int i = tid - 256;
        int r = i / WW, w = i - r * WW;
        hws[r][w] = fast_rcp(2.0f * (1.0f + (t - hist_time[(b0 + r) * WW + w])));
    }

    // ---- pre-A: target encoding, wave wv -> target wv (waves 0-3) ----
    if (wv < RPB) {
        int   tg  = targets[b0 + wv];
        float dtT = fabsf(t - adj_time[tg]);
        float gT  = gc[tg];
        float ph  = fmaf(t2v_w[lane], dtT, t2v_b[lane]);
        float tv_ = (lane == 0) ? ph : __cosf(ph);
        float f   = fmaxf(tv_ + fmaf(gT, node_w[lane], node_b[lane]), 0.f);
        float ss  = f * f;
#pragma unroll
        for (int off = 32; off; off >>= 1) ss += __shfl_xor(ss, off, 64);
        float invn = fast_rsq(fmaxf(ss, 1e-24f));
        float tfn  = f * invn;
        float sdt  = tfn * att_w[lane];
#pragma unroll
        for (int off = 32; off; off >>= 1) sdt += __shfl_xor(sdt, off, 64);
        if (lane == 0) stL[wv] = sdt;
        tile[wv * 256 + 128 + lane] = tfn;
    }
    __syncthreads();   // A: dtg{x,y}, hws, stL, tgt tile cols ready

    // ---- phase 1: full 64-dim in-lane per slot; params via uniform s_loads ----
    {
        const int   r  = slot >> 7;
        const float ab = att_b[0];
        float s2, sd;
        {   // d = 0: linear channel (no cos)
            float ph = fmaf(t2v_w[0], dt, t2v_b[0]);
            float f  = fmaxf(ph + fmaf(g, node_w[0], node_b[0]), 0.f);
            s2 = f * f;
            sd = f * att_w[64];
        }
#pragma unroll 4
        for (int d = 1; d < 64; ++d) {
            float ph = fmaf(t2v_w[d], dt, t2v_b[d]);
            float f  = fmaxf(__cosf(ph) + fmaf(g, node_w[d], node_b[d]), 0.f);
            s2 = fmaf(f, f, s2);
            sd = fmaf(f, att_w[64 + d], sd);
        }
        float invn = fast_rsq(fmaxf(s2, 1e-24f));
        float sc   = ts + stL[r] + sd * invn + ab;
        sc = (sc > 0.f) ? sc : 0.01f * sc;          // leaky_relu(0.01)
        dtg[slot].z = sc * m * invn;                // packed wk
    }

    // ---- history aggregation into tile cols 0-127 (threads 0-127, float4) ----
    if (tid < 128) {
        int r  = tid >> 5;          // 0..3
        int c4 = tid & 31;          // float4 column
        const float4* hf = (const float4*)(hist_feat + (size_t)(b0 + r) * WW * 128) + c4;
        float4 s4 = make_float4(0.f, 0.f, 0.f, 0.f);
#pragma unroll 4
        for (int w = 0; w < WW; ++w) {
            float  hw = hws[r][w];
            float4 v  = hf[w * 32];
            s4.x = fmaf(hw, v.x, s4.x);
            s4.y = fmaf(hw, v.y, s4.y);
            s4.z = fmaf(hw, v.z, s4.z);
            s4.w = fmaf(hw, v.w, s4.w);
        }
        *(float4*)(tile + r * 256 + c4 * 4) = s4;
    }
    __syncthreads();   // C: wk (dtg.z) ready

    // ---- phase 3: wave pair (2r, 2r+1) owns target r; 64 k's each ----
    const int r3   = wv >> 1;
    const int half = wv & 1;
    float acc3 = 0.f;
    {
        float sc  = (lane == 0) ? 1.f : INV2PI;     // lane 0 = linear channel
        float pw  = t2v_w[lane] * sc;
        float pb  = t2v_b[lane] * sc;
        float nw  = node_w[lane];
        float nb2 = node_b[lane];
        const int base = r3 * KK + half * 64;
#pragma unroll 4
        for (int k = 0; k < 64; ++k) {
            float4 dgw = dtg[base + k];             // uniform addr -> broadcast b128
            float  ph  = fmaf(pw, dgw.x, pb);
            float  cv  = __builtin_amdgcn_cosf(ph); // v_cos: cos(2*pi*ph)
            float  tv_ = lane ? cv : ph;
            float  f   = fmaxf(tv_ + fmaf(dgw.y, nw, nb2), 0.f);
            acc3 = fmaf(dgw.z, f, acc3);
        }
    }
    if (half) p3p[r3][lane] = acc3;
    __syncthreads();   // D: odd-wave partials ready
    if (!half) tile[r3 * 256 + 192 + lane] = acc3 + p3p[r3][lane];

    // ---- GEMM: out = relu(tile @ W^T); thread = (h, row), 1 row/thread ----
    const int h  = tid & 127;
    const int gg = tid >> 7;                        // row 0..3
    const float* tb = tile + gg * 256;
    float acc = 0.f;

    for (int c = 0; c < 8; ++c) {
        __syncthreads();   // c=0: covers phase-3 combine; else: wl reuse
#pragma unroll
        for (int i = 0; i < 8; ++i) {
            int l  = i * TPB + tid;
            int hh = l >> 5, jj = l & 31;
            wl[hh * 33 + jj] = weight[hh * 256 + c * 32 + jj];
        }
        __syncthreads();

#pragma unroll
        for (int jj = 0; jj < 32; jj += 4) {
            float w0 = wl[h * 33 + jj + 0];
            float w1 = wl[h * 33 + jj + 1];
            float w2 = wl[h * 33 + jj + 2];
            float w3 = wl[h * 33 + jj + 3];
            float4 f0 = *(const float4*)(tb + c * 32 + jj);
            acc += w0 * f0.x + w1 * f0.y + w2 * f0.z + w3 * f0.w;
        }
    }

    out[(size_t)(b0 + gg) * 128 + h] = fmaxf(acc, 0.f);
}

extern "C" void kernel_launch(void* const* d_in, const int* in_sizes, int n_in,
                              void* d_out, int out_size, void* d_ws, size_t ws_size,
                              hipStream_t stream) {
    const float* adj_time  = (const float*)d_in[0];
    const float* gc        = (const float*)d_in[1];
    const float* cur_time  = (const float*)d_in[2];
    const float* neigh_mask= (const float*)d_in[3];
    const float* hist_feat = (const float*)d_in[4];
    const float* hist_time = (const float*)d_in[5];
    const float* t2v_w     = (const float*)d_in[6];
    const float* t2v_b     = (const float*)d_in[7];
    const float* node_w    = (const float*)d_in[8];
    const float* node_b    = (const float*)d_in[9];
    const float* att_w     = (const float*)d_in[10];
    const float* att_b     = (const float*)d_in[11];
    const float* weight    = (const float*)d_in[12];
    const int*   targets   = (const int*)d_in[13];
    const int*   neigh_idx = (const int*)d_in[14];

    float* out = (float*)d_out;

    fused<<<BB / RPB, TPB, 0, stream>>>(adj_time, gc, cur_time, neigh_mask,
                                        hist_feat, hist_time, t2v_w, t2v_b,
                                        node_w, node_b, att_w, att_b, weight,
                                        targets, neigh_idx, out);
}

// Round 2
// 135.790 us; speedup vs baseline: 1.0180x; 1.0180x over previous
//
#include <hip/hip_runtime.h>
#include <math.h>

#define NN 200000
#define DD 64
#define BB 4096
#define KK 128
#define WW 20
#define HH 128
#define TPB 512
#define RPB 4    // targets per block; 8 waves = 2 waves per target

#define INV2PI 0.15915494309189535f

__device__ __forceinline__ float fast_rcp(float x) { return __builtin_amdgcn_rcpf(x); }
__device__ __forceinline__ float fast_rsq(float x) { return __builtin_amdgcn_rsqf(x); }
__device__ __forceinline__ float rlane(float v, int l) {
    return __int_as_float(__builtin_amdgcn_readlane(__float_as_int(v), l));
}

// Fully-fused pipeline, LDS-traffic-minimized: 1024 blocks x 512 threads,
// 4 targets/block, 2 waves/target (4 blocks/CU -> 32 waves/CU).
//   pre-A : 1 gather slot/thread into packed dtg{dt,g,wk,-}; hws; per-wave
//           target encodings (waves 0-3) straight into tile.
//   phase1: 1 slot/thread, 64-dim norm+att in-lane, wk -> dtg.z.
//   hist  : threads 0-127, float4 loads into tile cols 0-127.
//   phase3: wave pair (2r,2r+1) owns target r; lane k preloads dtg[k] (one
//           b128/wave), k-loop uses v_readlane broadcast (no LDS in loop).
//   GEMM  : thread = (h, j-quarter sq), 4 rows in registers; W chunk (32 j)
//           staged as XOR-swizzled float4 and read as ds_read_b128 -- each
//           W element touched exactly once per block. Partials combined via
//           the dead dtg buffer.
// feat4 never touches HBM; single launch.
__global__ __launch_bounds__(512, 8) void fused(
    const float* __restrict__ adj_time, const float* __restrict__ gc,
    const float* __restrict__ cur_time, const float* __restrict__ neigh_mask,
    const float* __restrict__ hist_feat, const float* __restrict__ hist_time,
    const float* __restrict__ t2v_w, const float* __restrict__ t2v_b,
    const float* __restrict__ node_w, const float* __restrict__ node_b,
    const float* __restrict__ att_w, const float* __restrict__ att_b,
    const float* __restrict__ weight,
    const int* __restrict__ targets, const int* __restrict__ neigh_idx,
    float* __restrict__ out)
{
    const int b0   = blockIdx.x * RPB;
    const int tid  = threadIdx.x;
    const int lane = tid & 63;
    const int wv   = tid >> 6;          // wave id 0..7

    __shared__ float4 dtg[RPB * KK];    // {dt, g, wk, -}; reused as partials  8 KB
    __shared__ float  hws[RPB][WW];     // history decay weights             320 B
    __shared__ float  stL[RPB];         // target att-dot per row
    __shared__ float  p3p[RPB][DD];     // phase-3 odd-wave partials           1 KB
    __shared__ float  tile[RPB * 256];  // feat4 rows                          4 KB
    __shared__ float4 wl4[128 * 8];     // W chunk [128 h][8 f4], XOR-swz     16 KB

    const float t = cur_time[0];

    // ---- pre-A: one gather slot per thread (slot = r*128 + k = tid) ----
    const int   slot = tid;
    const int   idx  = neigh_idx[b0 * KK + slot];
    const float m    = neigh_mask[b0 * KK + slot];
    const float at   = adj_time[idx];
    const float g    = gc[idx];
    const float dt   = fabsf(t - at);
    const float ts   = fast_rcp(2.0f * __logf(2.71828182845904523536f + (t - at)));
    dtg[slot] = make_float4(dt, g, 0.f, 0.f);

    // ---- pre-A: history decay weights (waves 4-5 region) ----
    if (tid >= 256 && tid < 256 + RPB * WW) {
        int i = tid - 256;
        int r = i / WW, w = i - r * WW;
        hws[r][w] = fast_rcp(2.0f * (1.0f + (t - hist_time[(b0 + r) * WW + w])));
    }

    // ---- pre-A: target encoding, wave wv -> target wv (waves 0-3) ----
    if (wv < RPB) {
        int   tg  = targets[b0 + wv];
        float dtT = fabsf(t - adj_time[tg]);
        float gT  = gc[tg];
        float ph  = fmaf(t2v_w[lane], dtT, t2v_b[lane]);
        float tv_ = (lane == 0) ? ph : __cosf(ph);
        float f   = fmaxf(tv_ + fmaf(gT, node_w[lane], node_b[lane]), 0.f);
        float ss  = f * f;
#pragma unroll
        for (int off = 32; off; off >>= 1) ss += __shfl_xor(ss, off, 64);
        float invn = fast_rsq(fmaxf(ss, 1e-24f));
        float tfn  = f * invn;
        float sdt  = tfn * att_w[lane];
#pragma unroll
        for (int off = 32; off; off >>= 1) sdt += __shfl_xor(sdt, off, 64);
        if (lane == 0) stL[wv] = sdt;
        tile[wv * 256 + 128 + lane] = tfn;
    }
    __syncthreads();   // A: dtg{x,y}, hws, stL, tgt tile cols ready

    // ---- phase 1: full 64-dim in-lane per slot; params via uniform s_loads ----
    {
        const int   r  = slot >> 7;
        const float ab = att_b[0];
        float s2, sd;
        {   // d = 0: linear channel (no cos)
            float ph = fmaf(t2v_w[0], dt, t2v_b[0]);
            float f  = fmaxf(ph + fmaf(g, node_w[0], node_b[0]), 0.f);
            s2 = f * f;
            sd = f * att_w[64];
        }
#pragma unroll 4
        for (int d = 1; d < 64; ++d) {
            float ph = fmaf(t2v_w[d], dt, t2v_b[d]);
            float f  = fmaxf(__cosf(ph) + fmaf(g, node_w[d], node_b[d]), 0.f);
            s2 = fmaf(f, f, s2);
            sd = fmaf(f, att_w[64 + d], sd);
        }
        float invn = fast_rsq(fmaxf(s2, 1e-24f));
        float sc   = ts + stL[r] + sd * invn + ab;
        sc = (sc > 0.f) ? sc : 0.01f * sc;          // leaky_relu(0.01)
        dtg[slot].z = sc * m * invn;                // packed wk
    }

    // ---- history aggregation into tile cols 0-127 (threads 0-127, float4) ----
    if (tid < 128) {
        int r  = tid >> 5;          // 0..3
        int c4 = tid & 31;          // float4 column
        const float4* hf = (const float4*)(hist_feat + (size_t)(b0 + r) * WW * 128) + c4;
        float4 s4 = make_float4(0.f, 0.f, 0.f, 0.f);
#pragma unroll 4
        for (int w = 0; w < WW; ++w) {
            float  hw = hws[r][w];
            float4 v  = hf[w * 32];
            s4.x = fmaf(hw, v.x, s4.x);
            s4.y = fmaf(hw, v.y, s4.y);
            s4.z = fmaf(hw, v.z, s4.z);
            s4.w = fmaf(hw, v.w, s4.w);
        }
        *(float4*)(tile + r * 256 + c4 * 4) = s4;
    }
    __syncthreads();   // C: wk (dtg.z) ready

    // ---- phase 3: wave pair (2r, 2r+1) owns target r; lane k holds dtg[k] ----
    const int r3   = wv >> 1;
    const int half = wv & 1;
    float4 myk = dtg[r3 * KK + half * 64 + lane];   // single b128 per lane
    float acc3 = 0.f;
    {
        float scn = (lane == 0) ? 1.f : INV2PI;     // lane 0 = linear channel
        float pw  = t2v_w[lane] * scn;
        float pb  = t2v_b[lane] * scn;
        float nw  = node_w[lane];
        float nb2 = node_b[lane];
#pragma unroll
        for (int k = 0; k < 64; ++k) {
            float kdt = rlane(myk.x, k);            // v_readlane broadcast
            float kg  = rlane(myk.y, k);
            float kw  = rlane(myk.z, k);
            float ph  = fmaf(pw, kdt, pb);
            float cv  = __builtin_amdgcn_cosf(ph);  // v_cos: cos(2*pi*ph)
            float tv_ = lane ? cv : ph;
            float f   = fmaxf(tv_ + fmaf(kg, nw, nb2), 0.f);
            acc3 = fmaf(kw, f, acc3);
        }
    }
    if (half) p3p[r3][lane] = acc3;
    __syncthreads();   // D: odd-wave partials ready; dtg dead after this point
    if (!half) tile[r3 * 256 + 192 + lane] = acc3 + p3p[r3][lane];

    // ---- GEMM: thread = (h, sq); 4 rows in registers; W read once/block ----
    const int h  = tid & 127;
    const int sq = tid >> 7;                        // j-quarter within chunk
    const int hx = h & 7;                           // XOR swizzle key
    const float4* w4g = (const float4*)weight;      // [128][64] float4 rows
    float accr[4] = {0.f, 0.f, 0.f, 0.f};

    for (int c = 0; c < 8; ++c) {
        __syncthreads();   // c=0: covers tile writes; else: wl4 reuse
#pragma unroll
        for (int i = 0; i < 2; ++i) {
            int l  = i * TPB + tid;                 // 0..1023
            int hh = l >> 3, gg = l & 7;
            wl4[hh * 8 + (gg ^ (hh & 7))] = w4g[hh * 64 + c * 8 + gg];
        }
        __syncthreads();

        float4 wa = wl4[h * 8 + ((sq * 2)     ^ hx)];   // j = c*32+sq*8 .. +3
        float4 wb = wl4[h * 8 + ((sq * 2 + 1) ^ hx)];   // j = c*32+sq*8+4 .. +7
        const int jb = c * 32 + sq * 8;
#pragma unroll
        for (int r = 0; r < 4; ++r) {
            float4 f0 = *(const float4*)(tile + r * 256 + jb);
            float4 f1 = *(const float4*)(tile + r * 256 + jb + 4);
            accr[r] += wa.x * f0.x + wa.y * f0.y + wa.z * f0.z + wa.w * f0.w
                     + wb.x * f1.x + wb.y * f1.y + wb.z * f1.z + wb.w * f1.w;
        }
    }

    // ---- combine 4 sq-partials per (row, h) via dead dtg buffer ----
    __syncthreads();                                // all chunk reads done
    float* prow = (float*)dtg;                      // 2048 floats
#pragma unroll
    for (int r = 0; r < 4; ++r)
        prow[(r * 4 + sq) * 128 + h] = accr[r];
    __syncthreads();
    {
        const int r2 = tid >> 7;
        float s = prow[(r2 * 4 + 0) * 128 + h] + prow[(r2 * 4 + 1) * 128 + h]
                + prow[(r2 * 4 + 2) * 128 + h] + prow[(r2 * 4 + 3) * 128 + h];
        out[(size_t)(b0 + r2) * 128 + h] = fmaxf(s, 0.f);
    }
}

extern "C" void kernel_launch(void* const* d_in, const int* in_sizes, int n_in,
                              void* d_out, int out_size, void* d_ws, size_t ws_size,
                              hipStream_t stream) {
    const float* adj_time  = (const float*)d_in[0];
    const float* gc        = (const float*)d_in[1];
    const float* cur_time  = (const float*)d_in[2];
    const float* neigh_mask= (const float*)d_in[3];
    const float* hist_feat = (const float*)d_in[4];
    const float* hist_time = (const float*)d_in[5];
    const float* t2v_w     = (const float*)d_in[6];
    const float* t2v_b     = (const float*)d_in[7];
    const float* node_w    = (const float*)d_in[8];
    const float* node_b    = (const float*)d_in[9];
    const float* att_w     = (const float*)d_in[10];
    const float* att_b     = (const float*)d_in[11];
    const float* weight    = (const float*)d_in[12];
    const int*   targets   = (const int*)d_in[13];
    const int*   neigh_idx = (const int*)d_in[14];

    float* out = (float*)d_out;

    fused<<<BB / RPB, TPB, 0, stream>>>(adj_time, gc, cur_time, neigh_mask,
                                        hist_feat, hist_time, t2v_w, t2v_b,
                                        node_w, node_b, att_w, att_b, weight,
                                        targets, neigh_idx, out);
}

// Round 3
// 133.935 us; speedup vs baseline: 1.0321x; 1.0139x over previous
//
#include <hip/hip_runtime.h>
#include <math.h>

#define NN 200000
#define DD 64
#define BB 4096
#define KK 128
#define WW 20
#define HH 128
#define TPB 512
#define RPB 4    // targets per block; 8 waves = 2 waves per target

#define INV2PI 0.15915494309189535f

__device__ __forceinline__ float fast_rcp(float x) { return __builtin_amdgcn_rcpf(x); }
__device__ __forceinline__ float fast_rsq(float x) { return __builtin_amdgcn_rsqf(x); }

// Fully-fused pipeline, barrier-minimized (5 block barriers, was ~21):
// 1024 blocks x 512 threads, 4 targets/block, 2 waves/target.
//   start : gathers (1 slot/thread) -> dtg{dt,g,-,-}; waves 6-7 run the
//           whole history aggregation early (private decay weights, HBM
//           latency hides under everyone's d-loop); waves 0-3 compute
//           target encodings -> stL + tile cols 128-191.
//   partA : 64-dim feature norm+att dot fully in-lane from registers
//           (no LDS deps) BEFORE the first barrier.
//   partB : finish score with stL, write wk -> dtg.z.
//   phase3: wave pair (2r,2r+1) owns target r; lane=dim; k-loop over 64
//           uniform ds_read_b128 broadcasts (LDS pipe is idle); partials
//           combined via p3p.
//   GEMM  : NO staging -- thread=(h, j-quarter) reads W float4 straight
//           from L2 (each element once per block), tile rows via uniform
//           LDS broadcasts; 4 row-partials combined through dead dtg.
// feat4 never touches HBM; single launch.
__global__ __launch_bounds__(512, 8) void fused(
    const float* __restrict__ adj_time, const float* __restrict__ gc,
    const float* __restrict__ cur_time, const float* __restrict__ neigh_mask,
    const float* __restrict__ hist_feat, const float* __restrict__ hist_time,
    const float* __restrict__ t2v_w, const float* __restrict__ t2v_b,
    const float* __restrict__ node_w, const float* __restrict__ node_b,
    const float* __restrict__ att_w, const float* __restrict__ att_b,
    const float* __restrict__ weight,
    const int* __restrict__ targets, const int* __restrict__ neigh_idx,
    float* __restrict__ out)
{
    const int b0   = blockIdx.x * RPB;
    const int tid  = threadIdx.x;
    const int lane = tid & 63;
    const int wv   = tid >> 6;          // wave id 0..7

    __shared__ float4 dtg[RPB * KK];    // {dt, g, wk, -}; reused as partials  8 KB
    __shared__ float  stL[RPB];         // target att-dot per row
    __shared__ float  p3p[RPB][DD];     // phase-3 odd-wave partials           1 KB
    __shared__ float  tile[RPB * 256];  // feat4 rows                          4 KB

    const float t = cur_time[0];

    // ---- gathers: one slot per thread (slot = r*128 + k = tid) ----
    const int   slot = tid;
    const int   idx  = neigh_idx[b0 * KK + slot];
    const float m    = neigh_mask[b0 * KK + slot];
    const float at   = adj_time[idx];
    const float g    = gc[idx];
    const float dt   = fabsf(t - at);
    const float ts   = fast_rcp(2.0f * __logf(2.71828182845904523536f + (t - at)));
    dtg[slot] = make_float4(dt, g, 0.f, 0.f);

    // ---- history aggregation, waves 6-7, fully self-contained ----
    if (tid >= 384) {
        const int r  = (tid >> 5) & 3;   // 0..3
        const int c4 = tid & 31;         // float4 column
        const float*  ht = hist_time + (size_t)(b0 + r) * WW;
        const float4* hf = (const float4*)(hist_feat + (size_t)(b0 + r) * WW * 128) + c4;
        float4 s4 = make_float4(0.f, 0.f, 0.f, 0.f);
#pragma unroll 4
        for (int w = 0; w < WW; ++w) {
            float  hw = fast_rcp(2.0f * (1.0f + (t - ht[w])));
            float4 v  = hf[w * 32];
            s4.x = fmaf(hw, v.x, s4.x);
            s4.y = fmaf(hw, v.y, s4.y);
            s4.z = fmaf(hw, v.z, s4.z);
            s4.w = fmaf(hw, v.w, s4.w);
        }
        *(float4*)(tile + r * 256 + c4 * 4) = s4;
    }

    // ---- target encoding, wave wv -> target wv (waves 0-3) ----
    if (wv < RPB) {
        int   tg  = targets[b0 + wv];
        float dtT = fabsf(t - adj_time[tg]);
        float gT  = gc[tg];
        float ph  = fmaf(t2v_w[lane], dtT, t2v_b[lane]);
        float tv_ = (lane == 0) ? ph : __cosf(ph);
        float f   = fmaxf(tv_ + fmaf(gT, node_w[lane], node_b[lane]), 0.f);
        float ss  = f * f;
#pragma unroll
        for (int off = 32; off; off >>= 1) ss += __shfl_xor(ss, off, 64);
        float invn = fast_rsq(fmaxf(ss, 1e-24f));
        float tfn  = f * invn;
        float sdt  = tfn * att_w[lane];
#pragma unroll
        for (int off = 32; off; off >>= 1) sdt += __shfl_xor(sdt, off, 64);
        if (lane == 0) stL[wv] = sdt;
        tile[wv * 256 + 128 + lane] = tfn;
    }

    // ---- part A: 64-dim in-lane norm+att from registers (no LDS deps) ----
    float s2, sd;
    {
        {   // d = 0: linear channel (no cos)
            float ph = fmaf(t2v_w[0], dt, t2v_b[0]);
            float f  = fmaxf(ph + fmaf(g, node_w[0], node_b[0]), 0.f);
            s2 = f * f;
            sd = f * att_w[64];
        }
#pragma unroll 4
        for (int d = 1; d < 64; ++d) {
            float ph = fmaf(t2v_w[d], dt, t2v_b[d]);
            float f  = fmaxf(__cosf(ph) + fmaf(g, node_w[d], node_b[d]), 0.f);
            s2 = fmaf(f, f, s2);
            sd = fmaf(f, att_w[64 + d], sd);
        }
    }
    __syncthreads();   // A: stL ready (dtg.xy, hist tile writes also done)

    // ---- part B: finish score, write wk ----
    {
        float invn = fast_rsq(fmaxf(s2, 1e-24f));
        float sc   = ts + stL[slot >> 7] + sd * invn + att_b[0];
        sc = (sc > 0.f) ? sc : 0.01f * sc;          // leaky_relu(0.01)
        dtg[slot].z = sc * m * invn;                // packed wk
    }
    __syncthreads();   // C: wk ready

    // ---- phase 3: wave pair (2r, 2r+1) owns target r; lane = dim ----
    const int r3   = wv >> 1;
    const int half = wv & 1;
    float acc3 = 0.f;
    {
        float scn = (lane == 0) ? 1.f : INV2PI;     // lane 0 = linear channel
        float pw  = t2v_w[lane] * scn;
        float pb  = t2v_b[lane] * scn;
        float nw  = node_w[lane];
        float nb2 = node_b[lane];
        const int base = r3 * KK + half * 64;
#pragma unroll 4
        for (int k = 0; k < 64; ++k) {
            float4 dgw = dtg[base + k];             // uniform addr -> broadcast b128
            float  ph  = fmaf(pw, dgw.x, pb);
            float  cv  = __builtin_amdgcn_cosf(ph); // v_cos: cos(2*pi*ph)
            float  tv_ = lane ? cv : ph;
            float  f   = fmaxf(tv_ + fmaf(dgw.y, nw, nb2), 0.f);
            acc3 = fmaf(dgw.z, f, acc3);
        }
    }
    if (half) p3p[r3][lane] = acc3;
    __syncthreads();   // D: odd-wave partials ready; dtg dead after this point
    if (!half) tile[r3 * 256 + 192 + lane] = acc3 + p3p[r3][lane];
    __syncthreads();   // E: tile complete

    // ---- GEMM: thread = (h, sq); W float4 straight from L2, once/block ----
    const int h  = tid & 127;
    const int sq = tid >> 7;                        // j-quarter 0..3
    const float4* w4 = (const float4*)weight + h * 64 + sq * 16;
    const int jb = sq * 64;
    float a0 = 0.f, a1 = 0.f, a2 = 0.f, a3 = 0.f;
#pragma unroll 4
    for (int j4 = 0; j4 < 16; ++j4) {
        float4 w  = w4[j4];
        const int jo = jb + j4 * 4;
        float4 f0 = *(const float4*)(tile + 0 * 256 + jo);   // uniform broadcasts
        float4 f1 = *(const float4*)(tile + 1 * 256 + jo);
        float4 f2 = *(const float4*)(tile + 2 * 256 + jo);
        float4 f3 = *(const float4*)(tile + 3 * 256 + jo);
        a0 += w.x * f0.x + w.y * f0.y + w.z * f0.z + w.w * f0.w;
        a1 += w.x * f1.x + w.y * f1.y + w.z * f1.z + w.w * f1.w;
        a2 += w.x * f2.x + w.y * f2.y + w.z * f2.z + w.w * f2.w;
        a3 += w.x * f3.x + w.y * f3.y + w.z * f3.z + w.w * f3.w;
    }

    // ---- combine 4 sq-partials per (row, h) via dead dtg buffer ----
    float* prow = (float*)dtg;                      // 2048 floats
    prow[(0 * 4 + sq) * 128 + h] = a0;
    prow[(1 * 4 + sq) * 128 + h] = a1;
    prow[(2 * 4 + sq) * 128 + h] = a2;
    prow[(3 * 4 + sq) * 128 + h] = a3;
    __syncthreads();   // F
    {
        const int r2 = tid >> 7;
        float s = prow[(r2 * 4 + 0) * 128 + h] + prow[(r2 * 4 + 1) * 128 + h]
                + prow[(r2 * 4 + 2) * 128 + h] + prow[(r2 * 4 + 3) * 128 + h];
        out[(size_t)(b0 + r2) * 128 + h] = fmaxf(s, 0.f);
    }
}

extern "C" void kernel_launch(void* const* d_in, const int* in_sizes, int n_in,
                              void* d_out, int out_size, void* d_ws, size_t ws_size,
                              hipStream_t stream) {
    const float* adj_time  = (const float*)d_in[0];
    const float* gc        = (const float*)d_in[1];
    const float* cur_time  = (const float*)d_in[2];
    const float* neigh_mask= (const float*)d_in[3];
    const float* hist_feat = (const float*)d_in[4];
    const float* hist_time = (const float*)d_in[5];
    const float* t2v_w     = (const float*)d_in[6];
    const float* t2v_b     = (const float*)d_in[7];
    const float* node_w    = (const float*)d_in[8];
    const float* node_b    = (const float*)d_in[9];
    const float* att_w     = (const float*)d_in[10];
    const float* att_b     = (const float*)d_in[11];
    const float* weight    = (const float*)d_in[12];
    const int*   targets   = (const int*)d_in[13];
    const int*   neigh_idx = (const int*)d_in[14];

    float* out = (float*)d_out;

    fused<<<BB / RPB, TPB, 0, stream>>>(adj_time, gc, cur_time, neigh_mask,
                                        hist_feat, hist_time, t2v_w, t2v_b,
                                        node_w, node_b, att_w, att_b, weight,
                                        targets, neigh_idx, out);
}